// Round 15
// baseline (171.194 us; speedup 1.0000x reference)
//
#include <hip/hip_runtime.h>
#include <math.h>

typedef _Float16 half_t;
typedef unsigned short ushort_t;
typedef unsigned char u8;

#define BATCH 4096
#define SEQL  512
#define NF    32
#define DEMB  8
#define DOUT  64

#define NWIN_TOTAL 3900
// float-index offsets in ws
#define MAXS_OFF   3968     // fp32 max score (after 3900 fp32 scores at 0)
#define HWIN_OFF   4096     // fp16 h-table, 3900*32 halves
#define TOFF       70000    // tap table T[14][5][32]
// byte offsets in ws
#define B_EH45     524288   // 3125 rows x 128 B : [E4*h4 (32 fp16) | E5*h5 (32 fp16)]
#define B_EH2      1048576  // 25  rows x 36 halves (72 B stride), E2*h2
#define B_EH3      1050376  // 125 rows x 36 halves, E3*h3
#define B_E2       1059376  // 25 fp16 (pad 64 B)
#define B_E3       1059440  // 125 fp16 (pad 256 B)
#define B_E4       1059696  // 625 fp16 (pad 1280 B)
#define B_E5       1060976  // 3125 fp16 (pad 6272 B)

union U8h { uint2 u; half_t h[4]; };

__device__ __forceinline__ float gelu_exact(float x) {
    return 0.5f * x * (1.0f + erff(x * 0.70710678118654752f));
}

// Stage A: tap table. T[tapg][d][f] = sum_c emb[d][c] * cw[f][c][t]
__global__ __launch_bounds__(256) void precompute_taps(
    const float* __restrict__ emb,
    const float* __restrict__ cw0, const float* __restrict__ cw1,
    const float* __restrict__ cw2, const float* __restrict__ cw3,
    float* __restrict__ ws)
{
    const int gid = blockIdx.x * blockDim.x + threadIdx.x;
    if (gid >= 14 * 5 * NF) return;
    const int f = gid & 31;
    const int r = gid >> 5;
    const int tapg = r / 5;
    const int d    = r % 5;

    int ks, t; const float* cw;
    if (tapg < 2)      { ks = 2; cw = cw0; t = tapg; }
    else if (tapg < 5) { ks = 3; cw = cw1; t = tapg - 2; }
    else if (tapg < 9) { ks = 4; cw = cw2; t = tapg - 5; }
    else               { ks = 5; cw = cw3; t = tapg - 9; }

    const float* e = emb + d * DEMB;
    float s = 0.0f;
#pragma unroll
    for (int c = 0; c < DEMB; ++c)
        s += e[c] * cw[(f * DEMB + c) * ks + t];
    ws[TOFF + r * NF + f] = s;
}

// Stage B: h-table (fp16) + fp32 scores at ws[0..3899].
__global__ __launch_bounds__(256) void precompute_windows(
    const float* __restrict__ cb0, const float* __restrict__ aw0, const float* __restrict__ ab0,
    const float* __restrict__ cb1, const float* __restrict__ aw1, const float* __restrict__ ab1,
    const float* __restrict__ cb2, const float* __restrict__ aw2, const float* __restrict__ ab2,
    const float* __restrict__ cb3, const float* __restrict__ aw3, const float* __restrict__ ab3,
    float* __restrict__ ws)
{
    const int gid = blockIdx.x * blockDim.x + threadIdx.x;
    if (gid >= NWIN_TOTAL * NF) return;
    const int wgid = gid >> 5;
    const int f    = gid & 31;

    int w, ks, cum;
    const float *cb, *aw, *ab;
    if (wgid < 25)       { w = wgid;       ks = 2; cum = 0; cb = cb0; aw = aw0; ab = ab0; }
    else if (wgid < 150) { w = wgid - 25;  ks = 3; cum = 2; cb = cb1; aw = aw1; ab = ab1; }
    else if (wgid < 775) { w = wgid - 150; ks = 4; cum = 5; cb = cb2; aw = aw2; ab = ab2; }
    else                 { w = wgid - 775; ks = 5; cum = 9; cb = cb3; aw = aw3; ab = ab3; }

    float h = cb[f];
    int ww = w;
    for (int t = ks - 1; t >= 0; --t) {
        int d = ww % 5; ww /= 5;
        h += ws[TOFF + ((cum + t) * 5 + d) * NF + f];
    }
    float g = gelu_exact(h);
    ((half_t*)(ws + HWIN_OFF))[wgid * NF + f] = (half_t)g;

    float s = g * aw[f];
#pragma unroll
    for (int off = 16; off; off >>= 1) s += __shfl_xor(s, off, 32);
    if (f == 0) ws[wgid] = s + ab[0];
}

// Stage B2: dynamic shift = max score (numerical safety for exp tables).
__global__ __launch_bounds__(256) void max_score(float* __restrict__ ws)
{
    __shared__ float red[4];
    float m = -1e30f;
    for (int i = threadIdx.x; i < NWIN_TOTAL; i += 256) m = fmaxf(m, ws[i]);
#pragma unroll
    for (int off = 32; off; off >>= 1) m = fmaxf(m, __shfl_xor(m, off));
    if ((threadIdx.x & 63) == 0) red[threadIdx.x >> 6] = m;
    __syncthreads();
    if (threadIdx.x == 0)
        ws[MAXS_OFF] = fmaxf(fmaxf(red[0], red[1]), fmaxf(red[2], red[3]));
}

// Stage C1: combined ks4/ks5 table, row w5 (128 B): [E4*h4 | E5*h5].
__global__ __launch_bounds__(256) void build_eh45(float* __restrict__ ws)
{
    const int gid = blockIdx.x * blockDim.x + threadIdx.x;
    if (gid >= 3125 * 16) return;
    const int w5  = gid >> 4;
    const int seg = gid & 15;
    const int br  = seg >> 3;                 // 0 -> ks4, 1 -> ks5
    const int q   = seg & 7;
    const int gw  = br ? (775 + w5) : (150 + w5 / 5);

    const float m = ws[MAXS_OFF];
    const float E = __expf(ws[gw] - m);
    const half_t* hp = (const half_t*)(ws + HWIN_OFF) + gw * NF + q * 4;
    U8h v;
#pragma unroll
    for (int j = 0; j < 4; ++j) v.h[j] = (half_t)(E * (float)hp[j]);
    *(uint2*)((char*)ws + B_EH45 + w5 * 128 + seg * 8) = v.u;
}

// Stage C2: small branch tables (E*h, stride 36 halves) + all E denominator tables.
__global__ __launch_bounds__(256) void build_small(float* __restrict__ ws)
{
    const int gid = blockIdx.x * blockDim.x + threadIdx.x;
    const float m = ws[MAXS_OFF];

    if (gid < 4800) {                       // eh2 / eh3 (+ e2 / e3 at f==0)
        const int row = gid >> 5;
        const int f   = gid & 31;
        int gw; half_t* dst; half_t* edst;
        if (row < 25) {
            gw  = row;
            dst = (half_t*)((char*)ws + B_EH2) + row * 36 + f;
            edst= (half_t*)((char*)ws + B_E2) + row;
        } else {
            const int w3 = row - 25;
            gw  = 25 + w3;
            dst = (half_t*)((char*)ws + B_EH3) + w3 * 36 + f;
            edst= (half_t*)((char*)ws + B_E3) + w3;
        }
        const float E = __expf(ws[gw] - m);
        const float h = (float)((const half_t*)(ws + HWIN_OFF))[gw * NF + f];
        *dst = (half_t)(E * h);
        if (f == 0) *edst = (half_t)E;
    } else if (gid < 5425) {                // e4 table
        const int w4 = gid - 4800;
        ((half_t*)((char*)ws + B_E4))[w4] = (half_t)__expf(ws[150 + w4] - m);
    } else if (gid < 8550) {                // e5 table
        const int w5 = gid - 5425;
        ((half_t*)((char*)ws + B_E5))[w5] = (half_t)__expf(ws[775 + w5] - m);
    }
}

__global__ __launch_bounds__(256) void fused_main(
    const int*   __restrict__ xidx,
    const float* __restrict__ ws,
    const float* __restrict__ projw, const float* __restrict__ projb,
    const float* __restrict__ gamma, const float* __restrict__ beta,
    float* __restrict__ out)
{
    __shared__ int      xs[SEQL + 8];
    __shared__ ushort_t w5id[SEQL];
    __shared__ u8       w2id[SEQL], w3id[SEQL];
    __shared__ half_t   eh2S[25 * 36];      // 1800 B, 72 B row stride
    __shared__ half_t   eh3S[125 * 36];     // 9000 B
    __shared__ half_t   e2S[32], e3S[128], e4S[640], e5S[3136];
    __shared__ float    partial45[4][16][4];
    __shared__ float    partial2[4][8][4], partial3[4][8][4];
    __shared__ float    redD[4][4];
    __shared__ float    feat[4 * NF];

    const int b   = blockIdx.x;
    const int tid = threadIdx.x;

    // ---- stage: tokens + LDS tables (all coalesced) ----
#pragma unroll
    for (int i = tid; i < SEQL / 4; i += 256)
        ((int4*)xs)[i] = ((const int4*)(xidx + b * SEQL))[i];
    if (tid < 8) xs[SEQL + tid] = 0;
    {
        const unsigned* g;
        g = (const unsigned*)((const char*)ws + B_EH2);
        for (int i = tid; i < 450;  i += 256) ((unsigned*)eh2S)[i] = g[i];
        g = (const unsigned*)((const char*)ws + B_EH3);
        for (int i = tid; i < 2250; i += 256) ((unsigned*)eh3S)[i] = g[i];
        g = (const unsigned*)((const char*)ws + B_E2);
        if (tid < 16) ((unsigned*)e2S)[tid] = g[tid];
        g = (const unsigned*)((const char*)ws + B_E3);
        if (tid < 64) ((unsigned*)e3S)[tid] = g[tid];
        g = (const unsigned*)((const char*)ws + B_E4);
        for (int i = tid; i < 320;  i += 256) ((unsigned*)e4S)[i] = g[i];
        g = (const unsigned*)((const char*)ws + B_E5);
        for (int i = tid; i < 1568; i += 256) ((unsigned*)e5S)[i] = g[i];
    }
    __syncthreads();

    const int wave = tid >> 6;
    const int lane = tid & 63;

    // ---- pass 1: window ids + denominators (all from LDS; no softmax) ----
    {
        float den2 = 0.f, den3 = 0.f, den4 = 0.f, den5 = 0.f;
#pragma unroll
        for (int it = 0; it < 2; ++it) {
            const int l = wave * 128 + it * 64 + lane;
            const int w2 = xs[l] * 5 + xs[l + 1];
            const int w3 = w2 * 5 + xs[l + 2];
            const int w4 = w3 * 5 + xs[l + 3];
            const int w5 = w4 * 5 + xs[l + 4];
            w5id[l] = (ushort_t)w5;
            w2id[l] = (u8)w2;
            w3id[l] = (u8)w3;
            if (l < 511) den2 += (float)e2S[w2];
            if (l < 510) den3 += (float)e3S[w3];
            if (l < 509) den4 += (float)e4S[w4];
            if (l < 508) den5 += (float)e5S[w5];
        }
#pragma unroll
        for (int off = 32; off; off >>= 1) {
            den2 += __shfl_xor(den2, off);
            den3 += __shfl_xor(den3, off);
            den4 += __shfl_xor(den4, off);
            den5 += __shfl_xor(den5, off);
        }
        if (lane == 0) {
            redD[wave][0] = den2; redD[wave][1] = den3;
            redD[wave][2] = den4; redD[wave][3] = den5;
        }
    }
    __syncthreads();

    // ---- pass 2a: THE scattered global stream — 128 B rows, 2 segs/position ----
    {
        const int o4  = lane >> 4;          // position within group of 4
        const int seg = lane & 15;
        const char* baseA = (const char*)ws + B_EH45 + seg * 8;
        const int limA = (seg < 8) ? 509 : 508;

        float a[4] = {0.f, 0.f, 0.f, 0.f};
#pragma unroll 8
        for (int it = 0; it < 32; ++it) {
            const int pos = wave * 128 + it * 4 + o4;
            const int w5 = w5id[pos];
            if (pos < limA) {
                U8h v; v.u = *(const uint2*)(baseA + w5 * 128);
#pragma unroll
                for (int j = 0; j < 4; ++j) a[j] += (float)v.h[j];
            }
        }
#pragma unroll
        for (int j = 0; j < 4; ++j) {
            a[j] += __shfl_xor(a[j], 16);
            a[j] += __shfl_xor(a[j], 32);
        }
        if (lane < 16) {
#pragma unroll
            for (int j = 0; j < 4; ++j) partial45[wave][seg][j] = a[j];
        }
    }

    // ---- pass 2b: small branches from LDS (off the TA pipe) ----
    {
        const int o8 = lane >> 3;           // position within group of 8
        const int r8 = lane & 7;
        float a2[4] = {0.f, 0.f, 0.f, 0.f};
        float a3[4] = {0.f, 0.f, 0.f, 0.f};
#pragma unroll 4
        for (int it = 0; it < 16; ++it) {
            const int pos = wave * 128 + it * 8 + o8;
            const int w2 = w2id[pos];
            const int w3 = w3id[pos];
            if (pos < 511) {
                U8h v; v.u = *(const uint2*)((const char*)eh2S + w2 * 72 + r8 * 8);
#pragma unroll
                for (int j = 0; j < 4; ++j) a2[j] += (float)v.h[j];
            }
            if (pos < 510) {
                U8h v; v.u = *(const uint2*)((const char*)eh3S + w3 * 72 + r8 * 8);
#pragma unroll
                for (int j = 0; j < 4; ++j) a3[j] += (float)v.h[j];
            }
        }
#pragma unroll
        for (int j = 0; j < 4; ++j) {
            a2[j] += __shfl_xor(a2[j], 8);  a3[j] += __shfl_xor(a3[j], 8);
            a2[j] += __shfl_xor(a2[j], 16); a3[j] += __shfl_xor(a3[j], 16);
            a2[j] += __shfl_xor(a2[j], 32); a3[j] += __shfl_xor(a3[j], 32);
        }
        if (lane < 8) {
#pragma unroll
            for (int j = 0; j < 4; ++j) {
                partial2[wave][lane][j] = a2[j];
                partial3[wave][lane][j] = a3[j];
            }
        }
    }
    __syncthreads();

    // ---- combine waves + normalize ----
    if (tid < 128) {
        const int c = tid >> 5;             // branch: 0=ks2,1=ks3,2=ks4,3=ks5
        const int f = tid & 31;
        const int r = f >> 2, j = f & 3;
        float num;
        if (c == 0)      num = partial2[0][r][j] + partial2[1][r][j]
                             + partial2[2][r][j] + partial2[3][r][j];
        else if (c == 1) num = partial3[0][r][j] + partial3[1][r][j]
                             + partial3[2][r][j] + partial3[3][r][j];
        else if (c == 2) num = partial45[0][r][j] + partial45[1][r][j]
                             + partial45[2][r][j] + partial45[3][r][j];
        else             num = partial45[0][8 + r][j] + partial45[1][8 + r][j]
                             + partial45[2][8 + r][j] + partial45[3][8 + r][j];
        const float d = redD[0][c] + redD[1][c] + redD[2][c] + redD[3][c];
        feat[tid] = num / d;
    }
    __syncthreads();

    // ---- projection + GELU + LayerNorm (wave 0) ----
    if (tid < DOUT) {
        float z = projb[tid];
        const float4* pwr = (const float4*)(projw + tid * (4 * NF));
#pragma unroll
        for (int q = 0; q < 32; ++q) {
            float4 wq = pwr[q];
            const float* fj = feat + q * 4;
            z += wq.x * fj[0] + wq.y * fj[1] + wq.z * fj[2] + wq.w * fj[3];
        }
        z = gelu_exact(z);

        float s1 = z, s2 = z * z;
#pragma unroll
        for (int off = 32; off; off >>= 1) {
            s1 += __shfl_xor(s1, off);
            s2 += __shfl_xor(s2, off);
        }
        const float mu  = s1 * (1.0f / 64.0f);
        const float var = s2 * (1.0f / 64.0f) - mu * mu;
        const float rr  = rsqrtf(var + 1e-5f);
        out[b * DOUT + tid] = (z - mu) * rr * gamma[tid] + beta[tid];
    }
}

extern "C" void kernel_launch(void* const* d_in, const int* in_sizes, int n_in,
                              void* d_out, int out_size, void* d_ws, size_t ws_size,
                              hipStream_t stream) {
    const int*   xidx = (const int*)d_in[0];
    const float* emb  = (const float*)d_in[1];
    const float* cw[4]; const float* cb[4]; const float* aw[4]; const float* ab[4];
    for (int i = 0; i < 4; ++i) {
        cw[i] = (const float*)d_in[2 + 4 * i];
        cb[i] = (const float*)d_in[3 + 4 * i];
        aw[i] = (const float*)d_in[4 + 4 * i];
        ab[i] = (const float*)d_in[5 + 4 * i];
    }
    const float* projw = (const float*)d_in[18];
    const float* projb = (const float*)d_in[19];
    const float* gm    = (const float*)d_in[20];
    const float* bt    = (const float*)d_in[21];
    float* ws  = (float*)d_ws;
    float* out = (float*)d_out;

    hipLaunchKernelGGL(precompute_taps, dim3((14 * 5 * NF + 255) / 256), dim3(256), 0, stream,
                       emb, cw[0], cw[1], cw[2], cw[3], ws);

    hipLaunchKernelGGL(precompute_windows, dim3((NWIN_TOTAL * NF + 255) / 256), dim3(256), 0, stream,
                       cb[0], aw[0], ab[0],
                       cb[1], aw[1], ab[1],
                       cb[2], aw[2], ab[2],
                       cb[3], aw[3], ab[3],
                       ws);

    hipLaunchKernelGGL(max_score, dim3(1), dim3(256), 0, stream, ws);

    hipLaunchKernelGGL(build_eh45, dim3((3125 * 16 + 255) / 256), dim3(256), 0, stream, ws);

    hipLaunchKernelGGL(build_small, dim3((8550 + 255) / 256), dim3(256), 0, stream, ws);

    hipLaunchKernelGGL(fused_main, dim3(BATCH), dim3(256), 0, stream,
                       xidx, ws, projw, projb, gm, bt, out);
}